// Round 1
// baseline (22641.289 us; speedup 1.0000x reference)
//
#include <hip/hip_runtime.h>
#include <stdint.h>

// ---------------------------------------------------------------------------
// Problem constants
// ---------------------------------------------------------------------------
#define B   4096
#define F   512
#define H   256
#define E   128
#define V   32000
#define TT  16
#define OC  17          // output columns (16 steps + zero col)
#define NCH 6           // V-chunks per row-block in the big kernel

// ---------------------------------------------------------------------------
// Threefry-2x32 (20 rounds) — matches jax._src.prng.threefry2x32 exactly.
// Partitionable counter-mode: bits(i) = x0^x1 at counter (0, i).
// split foldlike: key_t = (x0, x1) at counter (0, t) under parent key.
// ---------------------------------------------------------------------------
__host__ __device__ __forceinline__ uint32_t tf_rotl(uint32_t x, int r) {
    return (x << r) | (x >> (32 - r));
}

#define TF_R(rot) { x0 += x1; x1 = tf_rotl(x1, rot); x1 ^= x0; }

__host__ __device__ __forceinline__ void tf2x32(uint32_t k0, uint32_t k1,
                                                uint32_t c0, uint32_t c1,
                                                uint32_t& o0, uint32_t& o1) {
    uint32_t k2 = k0 ^ k1 ^ 0x1BD11BDAu;
    uint32_t x0 = c0 + k0, x1 = c1 + k1;
    TF_R(13) TF_R(15) TF_R(26) TF_R(6)
    x0 += k1; x1 += k2 + 1u;
    TF_R(17) TF_R(29) TF_R(16) TF_R(24)
    x0 += k2; x1 += k0 + 2u;
    TF_R(13) TF_R(15) TF_R(26) TF_R(6)
    x0 += k0; x1 += k1 + 3u;
    TF_R(17) TF_R(29) TF_R(16) TF_R(24)
    x0 += k1; x1 += k2 + 4u;
    TF_R(13) TF_R(15) TF_R(26) TF_R(6)
    x0 += k2; x1 += k0 + 5u;
    o0 = x0; o1 = x1;
}

// ---------------------------------------------------------------------------
// init: c=0, inp=broadcast(sos), zero final output column (d_out is poisoned)
// ---------------------------------------------------------------------------
__global__ void k_init(float* __restrict__ c, float* __restrict__ inp,
                       const float* __restrict__ sos, float* __restrict__ out) {
    int i = blockIdx.x * 256 + threadIdx.x;
    if (i < B * H) c[i] = 0.f;
    if (i < B * E) inp[i] = sos[i & (E - 1)];
    if (i < 3 * B) {
        int o = i >> 12, r = i & (B - 1);
        out[(size_t)o * (B * OC) + (size_t)r * OC + (OC - 1)] = 0.f;
    }
}

// ---------------------------------------------------------------------------
// h0 = x @ W_in.T + b_in     [4096,256] = [4096,512] @ [512,256]
// block: 16 rows x 256 n, K=512 in 32 chunks of 16. 256 threads.
// thread: 4 b (wave-uniform) x 4 n (contiguous). LDS: xs 32KB + wt 16.6KB.
// ---------------------------------------------------------------------------
__global__ __launch_bounds__(256) void k_h0(const float* __restrict__ x,
                                            const float* __restrict__ W_in,
                                            const float* __restrict__ b_in,
                                            float* __restrict__ h) {
    __shared__ float xs[16 * 512];
    __shared__ float wt[16 * 260];
    const int tid = threadIdx.x;
    const int r0 = blockIdx.x * 16;

#pragma unroll
    for (int p = 0; p < 8; p++) {               // stage x tile [16][512]
        int ff = tid + 256 * p, row = ff >> 7, c4 = ff & 127;
        *(float4*)&xs[row * 512 + c4 * 4] =
            *(const float4*)(x + (size_t)(r0 + row) * 512 + c4 * 4);
    }
    const int g = tid >> 6, l = tid & 63;
    float acc[4][4] = {{0.f}};

    for (int kc = 0; kc < 32; kc++) {
        __syncthreads();
#pragma unroll
        for (int p = 0; p < 4; p++) {           // stage W_in[n][kc*16..] transposed
            int ff = tid + 256 * p, rl = ff >> 2, k4 = ff & 3;
            float4 w = *(const float4*)(W_in + (size_t)rl * 512 + kc * 16 + k4 * 4);
            wt[(k4 * 4 + 0) * 260 + rl] = w.x;
            wt[(k4 * 4 + 1) * 260 + rl] = w.y;
            wt[(k4 * 4 + 2) * 260 + rl] = w.z;
            wt[(k4 * 4 + 3) * 260 + rl] = w.w;
        }
        __syncthreads();
#pragma unroll
        for (int kk = 0; kk < 16; kk += 4) {
            float4 w0 = *(const float4*)&wt[(kk + 0) * 260 + 4 * l];
            float4 w1 = *(const float4*)&wt[(kk + 1) * 260 + 4 * l];
            float4 w2 = *(const float4*)&wt[(kk + 2) * 260 + 4 * l];
            float4 w3 = *(const float4*)&wt[(kk + 3) * 260 + 4 * l];
#pragma unroll
            for (int b = 0; b < 4; b++) {
                float4 xb = *(const float4*)&xs[(4 * g + b) * 512 + kc * 16 + kk];
                acc[b][0] = fmaf(xb.w, w3.x, fmaf(xb.z, w2.x, fmaf(xb.y, w1.x, fmaf(xb.x, w0.x, acc[b][0]))));
                acc[b][1] = fmaf(xb.w, w3.y, fmaf(xb.z, w2.y, fmaf(xb.y, w1.y, fmaf(xb.x, w0.y, acc[b][1]))));
                acc[b][2] = fmaf(xb.w, w3.z, fmaf(xb.z, w2.z, fmaf(xb.y, w1.z, fmaf(xb.x, w0.z, acc[b][2]))));
                acc[b][3] = fmaf(xb.w, w3.w, fmaf(xb.z, w2.w, fmaf(xb.y, w1.w, fmaf(xb.x, w0.w, acc[b][3]))));
            }
        }
    }
    float4 bi = *(const float4*)(b_in + 4 * l);
#pragma unroll
    for (int b = 0; b < 4; b++) {
        float4 o = make_float4(acc[b][0] + bi.x, acc[b][1] + bi.y,
                               acc[b][2] + bi.z, acc[b][3] + bi.w);
        *(float4*)(h + (size_t)(r0 + 4 * g + b) * 256 + 4 * l) = o;
    }
}

// ---------------------------------------------------------------------------
// gates = inp @ W_ih.T + b_ih + h @ W_hh.T + b_hh, fused LSTM cell update.
// block: 16 rows x (4 gates x 64 u), K=384 in 12 chunks of 32.
// row_local rl in [0,256): gate = rl>>6, ul = rl&63, W row = gate*256+u0+ul.
// After GEMM: exchange gates through LDS (reuse wt) -> pointwise LSTM.
// ---------------------------------------------------------------------------
__global__ __launch_bounds__(256) void k_gates_lstm(
    const float* __restrict__ inp, const float* __restrict__ hcur,
    const float* __restrict__ W_ih, const float* __restrict__ W_hh,
    const float* __restrict__ b_ih, const float* __restrict__ b_hh,
    float* __restrict__ c, float* __restrict__ hnxt) {
    __shared__ float xs[16 * 384];
    __shared__ float wt[32 * 260];      // reused as gl[16*256] for the exchange
    const int tid = threadIdx.x;
    const int r0 = blockIdx.x * 16;
    const int u0 = blockIdx.y * 64;

#pragma unroll
    for (int p = 0; p < 2; p++) {               // stage inp [16][128] -> cols [0,128)
        int ff = tid + 256 * p, row = ff >> 5, c4 = ff & 31;
        *(float4*)&xs[row * 384 + c4 * 4] =
            *(const float4*)(inp + (size_t)(r0 + row) * 128 + c4 * 4);
    }
#pragma unroll
    for (int p = 0; p < 4; p++) {               // stage h [16][256] -> cols [128,384)
        int ff = tid + 256 * p, row = ff >> 6, c4 = ff & 63;
        *(float4*)&xs[row * 384 + 128 + c4 * 4] =
            *(const float4*)(hcur + (size_t)(r0 + row) * 256 + c4 * 4);
    }
    const int g = tid >> 6, l = tid & 63;
    float acc[4][4] = {{0.f}};

    for (int kc = 0; kc < 12; kc++) {
        __syncthreads();
        {
            const float* src; int rowlen, koff;
            if (kc < 4) { src = W_ih; rowlen = 128; koff = kc * 32; }
            else        { src = W_hh; rowlen = 256; koff = (kc - 4) * 32; }
#pragma unroll
            for (int p = 0; p < 8; p++) {
                int rl = (tid >> 3) + 32 * p;   // row_local 0..255
                int k4 = tid & 7;
                int grow = ((rl >> 6) << 8) + u0 + (rl & 63);
                float4 w = *(const float4*)(src + (size_t)grow * rowlen + koff + k4 * 4);
                wt[(k4 * 4 + 0) * 260 + rl] = w.x;
                wt[(k4 * 4 + 1) * 260 + rl] = w.y;
                wt[(k4 * 4 + 2) * 260 + rl] = w.z;
                wt[(k4 * 4 + 3) * 260 + rl] = w.w;
            }
        }
        __syncthreads();
#pragma unroll
        for (int kk = 0; kk < 32; kk += 4) {
            float4 w0 = *(const float4*)&wt[(kk + 0) * 260 + 4 * l];
            float4 w1 = *(const float4*)&wt[(kk + 1) * 260 + 4 * l];
            float4 w2 = *(const float4*)&wt[(kk + 2) * 260 + 4 * l];
            float4 w3 = *(const float4*)&wt[(kk + 3) * 260 + 4 * l];
#pragma unroll
            for (int b = 0; b < 4; b++) {
                float4 xb = *(const float4*)&xs[(4 * g + b) * 384 + kc * 32 + kk];
                acc[b][0] = fmaf(xb.w, w3.x, fmaf(xb.z, w2.x, fmaf(xb.y, w1.x, fmaf(xb.x, w0.x, acc[b][0]))));
                acc[b][1] = fmaf(xb.w, w3.y, fmaf(xb.z, w2.y, fmaf(xb.y, w1.y, fmaf(xb.x, w0.y, acc[b][1]))));
                acc[b][2] = fmaf(xb.w, w3.z, fmaf(xb.z, w2.z, fmaf(xb.y, w1.z, fmaf(xb.x, w0.z, acc[b][2]))));
                acc[b][3] = fmaf(xb.w, w3.w, fmaf(xb.z, w2.w, fmaf(xb.y, w1.w, fmaf(xb.x, w0.w, acc[b][3]))));
            }
        }
    }
    {   // bias (zeros in practice, but keep exact semantics)
        int rl0 = 4 * l;
        int grow0 = ((rl0 >> 6) << 8) + u0 + (rl0 & 63);
        float4 bi = *(const float4*)(b_ih + grow0);
        float4 bh = *(const float4*)(b_hh + grow0);
#pragma unroll
        for (int b = 0; b < 4; b++) {
            acc[b][0] += bi.x + bh.x; acc[b][1] += bi.y + bh.y;
            acc[b][2] += bi.z + bh.z; acc[b][3] += bi.w + bh.w;
        }
    }
    __syncthreads();
    float* gl = wt;                              // [16][256]: gate*64+ul per row
#pragma unroll
    for (int b = 0; b < 4; b++)
        *(float4*)&gl[(4 * g + b) * 256 + 4 * l] =
            make_float4(acc[b][0], acc[b][1], acc[b][2], acc[b][3]);
    __syncthreads();
    {   // LSTM pointwise: thread -> (bl = tid>>4, 4 u's)
        int bl = tid >> 4, uq = tid & 15;
        size_t cidx = (size_t)(r0 + bl) * 256 + u0 + uq * 4;
        float4 cold4 = *(float4*)(c + cidx);
        float4 cv, hv;
#pragma unroll
        for (int j = 0; j < 4; j++) {
            int ul = uq * 4 + j;
            float gi = gl[bl * 256 + ul];
            float gf = gl[bl * 256 + 64 + ul];
            float gg = gl[bl * 256 + 128 + ul];
            float go = gl[bl * 256 + 192 + ul];
            // XLA logistic-expander form: 0.5 + 0.5*tanh(0.5x)
            float si = fmaf(0.5f, tanhf(0.5f * gi), 0.5f);
            float sf = fmaf(0.5f, tanhf(0.5f * gf), 0.5f);
            float so = fmaf(0.5f, tanhf(0.5f * go), 0.5f);
            float tg = tanhf(gg);
            float cold = (&cold4.x)[j];
            float cn = sf * cold + si * tg;
            (&cv.x)[j] = cn;
            (&hv.x)[j] = so * tanhf(cn);
        }
        *(float4*)(c + cidx) = cv;
        *(float4*)(hnxt + cidx) = hv;
    }
}

// ---------------------------------------------------------------------------
// Fused logits + gumbel + online (sum-exp, sum-exp*l, argmax of l+g).
// grid = 128 row-blocks x NCH chunks. block: 32 rows, 256 v per tile.
// thread: 8 rows (wave-uniform) x 4 v (contiguous). Fixed shift exp(l-20)
// (|l| <= ~17 given |h|<~5.5, row norms ~1) -> no running-max rescale.
// ---------------------------------------------------------------------------
__global__ __launch_bounds__(256) void k_logits_sample(
    const float* __restrict__ hn, const float* __restrict__ W_out,
    const float* __restrict__ b_out, unsigned key0, unsigned key1,
    float* __restrict__ part) {
    __shared__ float hs[32 * 256];
    __shared__ float wt[16 * 260];
    const int tid = threadIdx.x;
    const int bblk = blockIdx.x / NCH;
    const int chunk = blockIdx.x % NCH;
    const int r0 = bblk * 32;

#pragma unroll
    for (int p = 0; p < 8; p++) {               // stage h tile [32][256]
        int ff = tid + 256 * p, row = ff >> 6, c4 = ff & 63;
        *(float4*)&hs[row * 256 + c4 * 4] =
            *(const float4*)(hn + (size_t)(r0 + row) * 256 + c4 * 4);
    }
    const int g = tid >> 6, l = tid & 63;

    float S[8], Ts[8], U[8], La[8]; int Ai[8];
#pragma unroll
    for (int b = 0; b < 8; b++) { S[b] = 0.f; Ts[b] = 0.f; U[b] = -3.4e38f; La[b] = 0.f; Ai[b] = 0; }

    for (int tile = chunk; tile < V / 256; tile += NCH) {
        const int v0 = tile * 256;
        float acc[8][4];
#pragma unroll
        for (int b = 0; b < 8; b++) { acc[b][0] = 0.f; acc[b][1] = 0.f; acc[b][2] = 0.f; acc[b][3] = 0.f; }

        for (int kc = 0; kc < 16; kc++) {
            __syncthreads();
#pragma unroll
            for (int p = 0; p < 4; p++) {       // stage W_out[v0+rl][kc*16..] transposed
                int ff = tid + 256 * p, rl = ff >> 2, k4 = ff & 3;
                float4 w = *(const float4*)(W_out + (size_t)(v0 + rl) * 256 + kc * 16 + k4 * 4);
                wt[(k4 * 4 + 0) * 260 + rl] = w.x;
                wt[(k4 * 4 + 1) * 260 + rl] = w.y;
                wt[(k4 * 4 + 2) * 260 + rl] = w.z;
                wt[(k4 * 4 + 3) * 260 + rl] = w.w;
            }
            __syncthreads();
#pragma unroll
            for (int kk = 0; kk < 16; kk += 4) {
                float4 w0 = *(const float4*)&wt[(kk + 0) * 260 + 4 * l];
                float4 w1 = *(const float4*)&wt[(kk + 1) * 260 + 4 * l];
                float4 w2 = *(const float4*)&wt[(kk + 2) * 260 + 4 * l];
                float4 w3 = *(const float4*)&wt[(kk + 3) * 260 + 4 * l];
#pragma unroll
                for (int b = 0; b < 8; b++) {
                    float4 hb = *(const float4*)&hs[(8 * g + b) * 256 + kc * 16 + kk];
                    acc[b][0] = fmaf(hb.w, w3.x, fmaf(hb.z, w2.x, fmaf(hb.y, w1.x, fmaf(hb.x, w0.x, acc[b][0]))));
                    acc[b][1] = fmaf(hb.w, w3.y, fmaf(hb.z, w2.y, fmaf(hb.y, w1.y, fmaf(hb.x, w0.y, acc[b][1]))));
                    acc[b][2] = fmaf(hb.w, w3.z, fmaf(hb.z, w2.z, fmaf(hb.y, w1.z, fmaf(hb.x, w0.z, acc[b][2]))));
                    acc[b][3] = fmaf(hb.w, w3.w, fmaf(hb.z, w2.w, fmaf(hb.y, w1.w, fmaf(hb.x, w0.w, acc[b][3]))));
                }
            }
        }
        float4 bo = *(const float4*)(b_out + v0 + 4 * l);
#pragma unroll
        for (int b = 0; b < 8; b++) {
            const unsigned row = (unsigned)(r0 + 8 * g + b);
            const unsigned base = row * (unsigned)V + (unsigned)(v0 + 4 * l);
#pragma unroll
            for (int j = 0; j < 4; j++) {
                float lg = acc[b][j] + (&bo.x)[j];
                float e = __expf(lg - 20.f);
                S[b] += e;
                Ts[b] = fmaf(e, lg, Ts[b]);
                // JAX partitionable random bits: x0^x1 at counter (0, flat_idx)
                unsigned o0, o1;
                tf2x32(key0, key1, 0u, base + (unsigned)j, o0, o1);
                unsigned bits = o0 ^ o1;
                float f = __uint_as_float((bits >> 9) | 0x3f800000u) - 1.0f;
                float uu = fmaxf(1.17549435e-38f, f + 1.17549435e-38f);
                float gmb = -logf(-logf(uu));   // accurate logf: rel. precision at u~1
                float u = lg + gmb;
                int vidx = v0 + 4 * l + j;
                if (u > U[b] || (u == U[b] && vidx < Ai[b])) { U[b] = u; Ai[b] = vidx; La[b] = lg; }
            }
        }
    }
    // wave-level reduction (64 lanes share the same 8 rows)
#pragma unroll
    for (int b = 0; b < 8; b++) {
        float s = S[b], ts = Ts[b], u = U[b], la = La[b]; int a = Ai[b];
#pragma unroll
        for (int off = 1; off < 64; off <<= 1) {
            s  += __shfl_xor(s, off);
            ts += __shfl_xor(ts, off);
            float u2 = __shfl_xor(u, off);
            float la2 = __shfl_xor(la, off);
            int a2 = __shfl_xor(a, off);
            if (u2 > u || (u2 == u && a2 < a)) { u = u2; a = a2; la = la2; }
        }
        if (l == 0) {
            float* p = part + (size_t)(r0 + 8 * g + b) * (NCH * 8) + chunk * 8;
            p[0] = s; p[1] = ts; p[2] = u; p[3] = la;
            ((int*)p)[4] = a;
        }
    }
}

// ---------------------------------------------------------------------------
// Combine NCH partials per row -> sample, logp, entropy, emb gather.
// block: 8 rows x 32 lanes.
// ---------------------------------------------------------------------------
__global__ __launch_bounds__(256) void k_sample_out(
    const float* __restrict__ part, const float* __restrict__ emb,
    float* __restrict__ inp, float* __restrict__ out, int step) {
    const int tid = threadIdx.x;
    const int row = blockIdx.x * 8 + (tid >> 5);
    const int lane = tid & 31;
    const float* p = part + (size_t)row * (NCH * 8);
    float s = 0.f, ts = 0.f, u = -3.4e38f, la = 0.f; int a = 0;
    for (int cg = 0; cg < NCH; cg++) {
        const float* q = p + cg * 8;
        s += q[0]; ts += q[1];
        float uc = q[2]; int ac = ((const int*)q)[4];
        if (uc > u || (uc == u && ac < a)) { u = uc; a = ac; la = q[3]; }
    }
    float lse = logf(s) + 20.f;
    if (lane == 0) {
        out[(size_t)row * OC + step] = (float)a;
        out[(size_t)B * OC + (size_t)row * OC + step] = la - lse;
        out[(size_t)2 * B * OC + (size_t)row * OC + step] = lse - ts / s;
    }
    float4 e4 = *(const float4*)(emb + (size_t)a * 128 + lane * 4);
    *(float4*)&inp[(size_t)row * 128 + lane * 4] = e4;
}

// ---------------------------------------------------------------------------
// Host
// ---------------------------------------------------------------------------
extern "C" void kernel_launch(void* const* d_in, const int* in_sizes, int n_in,
                              void* d_out, int out_size, void* d_ws, size_t ws_size,
                              hipStream_t stream) {
    (void)in_sizes; (void)n_in; (void)out_size; (void)ws_size;
    const float* x     = (const float*)d_in[0];
    const float* W_in  = (const float*)d_in[1];
    const float* b_in  = (const float*)d_in[2];
    const float* W_out = (const float*)d_in[3];
    const float* b_out = (const float*)d_in[4];
    const float* emb   = (const float*)d_in[5];
    const float* sos   = (const float*)d_in[6];
    const float* W_ih  = (const float*)d_in[7];
    const float* W_hh  = (const float*)d_in[8];
    const float* b_ih  = (const float*)d_in[9];
    const float* b_hh  = (const float*)d_in[10];
    float* out = (float*)d_out;
    float* ws  = (float*)d_ws;

    float* hA   = ws;                      // B*H
    float* hB   = ws + 1048576;            // B*H
    float* cc   = ws + 2097152;            // B*H
    float* inp  = ws + 3145728;            // B*E
    float* part = ws + 3670016;            // B * NCH * 8

    // step keys: foldlike split of key(42) = (0,42): key_t = block at (0, t)
    unsigned K0[TT], K1[TT];
    for (int t = 0; t < TT; t++) {
        uint32_t o0, o1;
        tf2x32(0u, 42u, 0u, (uint32_t)t, o0, o1);
        K0[t] = o0; K1[t] = o1;
    }

    k_init<<<4096, 256, 0, stream>>>(cc, inp, sos, out);
    k_h0<<<B / 16, 256, 0, stream>>>(x, W_in, b_in, hA);

    float* hc = hA;
    float* hn = hB;
    for (int t = 0; t < TT; t++) {
        k_gates_lstm<<<dim3(B / 16, 4), 256, 0, stream>>>(inp, hc, W_ih, W_hh,
                                                          b_ih, b_hh, cc, hn);
        k_logits_sample<<<(B / 32) * NCH, 256, 0, stream>>>(hn, W_out, b_out,
                                                            K0[t], K1[t], part);
        k_sample_out<<<B / 8, 256, 0, stream>>>(part, emb, inp, out, t);
        float* tmp = hc; hc = hn; hn = tmp;
    }
}

// Round 4
// 13713.052 us; speedup vs baseline: 1.6511x; 1.6511x over previous
//
#include <hip/hip_runtime.h>
#include <stdint.h>

// ---------------------------------------------------------------------------
// Problem constants
// ---------------------------------------------------------------------------
#define B   4096
#define F   512
#define H   256
#define E   128
#define V   32000
#define TT  16
#define OC  17          // output columns (16 steps + zero col)
#define NCH 6           // V-chunks per row-block in the logits kernel
#define NTILES 250      // V / 128
#define NSLOT (NCH * 4) // partials per row: chunks x waves
#define RSCALE 2048.0f
#define RINV   4.8828125e-4f   // 1/2048

typedef _Float16 half8 __attribute__((ext_vector_type(8)));
typedef float f32x4 __attribute__((ext_vector_type(4)));
typedef unsigned short us8 __attribute__((ext_vector_type(8)));

// ---------------------------------------------------------------------------
// Threefry-2x32 (20 rounds) — matches jax._src.prng.threefry2x32 exactly.
// Partitionable counter-mode: bits(i) = x0^x1 at counter (0, i).
// ---------------------------------------------------------------------------
__host__ __device__ __forceinline__ uint32_t tf_rotl(uint32_t x, int r) {
    return (x << r) | (x >> (32 - r));
}

#define TF_R(rot) { x0 += x1; x1 = tf_rotl(x1, rot); x1 ^= x0; }

__host__ __device__ __forceinline__ void tf2x32(uint32_t k0, uint32_t k1,
                                                uint32_t c0, uint32_t c1,
                                                uint32_t& o0, uint32_t& o1) {
    uint32_t k2 = k0 ^ k1 ^ 0x1BD11BDAu;
    uint32_t x0 = c0 + k0, x1 = c1 + k1;
    TF_R(13) TF_R(15) TF_R(26) TF_R(6)
    x0 += k1; x1 += k2 + 1u;
    TF_R(17) TF_R(29) TF_R(16) TF_R(24)
    x0 += k2; x1 += k0 + 2u;
    TF_R(13) TF_R(15) TF_R(26) TF_R(6)
    x0 += k0; x1 += k1 + 3u;
    TF_R(17) TF_R(29) TF_R(16) TF_R(24)
    x0 += k1; x1 += k2 + 4u;
    TF_R(13) TF_R(15) TF_R(26) TF_R(6)
    x0 += k2; x1 += k0 + 5u;
    o0 = x0; o1 = x1;
}

// f16x2 split with SCALED residual: x ~= p1 + p2/2048, p2 = f16(2048*(x-p1)).
// Scaling keeps the residual plane in f16-normal range. Error ~2^-22 |x|.
__device__ __forceinline__ void split2h(float x, unsigned short& u1, unsigned short& u2) {
    _Float16 a = (_Float16)x;
    float r = (x - (float)a) * RSCALE;
    _Float16 b = (_Float16)r;
    u1 = __builtin_bit_cast(unsigned short, a);
    u2 = __builtin_bit_cast(unsigned short, b);
}

// ---------------------------------------------------------------------------
// init: c=0, inp=broadcast(sos), zero final output column (d_out is poisoned)
// ---------------------------------------------------------------------------
__global__ void k_init(float* __restrict__ c, float* __restrict__ inp,
                       const float* __restrict__ sos, float* __restrict__ out) {
    int i = blockIdx.x * 256 + threadIdx.x;
    if (i < B * H) c[i] = 0.f;
    if (i < B * E) inp[i] = sos[i & (E - 1)];
    if (i < 3 * B) {
        int o = i >> 12, r = i & (B - 1);
        out[(size_t)o * (B * OC) + (size_t)r * OC + (OC - 1)] = 0.f;
    }
}

// ---------------------------------------------------------------------------
// W_out f16x2 split planes (once per launch): wb1/wb2 ushort [V][256]
// ---------------------------------------------------------------------------
__global__ __launch_bounds__(256) void k_wsplit(const float* __restrict__ W,
                                                unsigned short* __restrict__ w1,
                                                unsigned short* __restrict__ w2) {
    int i = blockIdx.x * 256 + threadIdx.x;       // float4 index, V*H/4 total
    float4 v = *(const float4*)(W + (size_t)i * 4);
    ushort4 p1, p2;
    split2h(v.x, p1.x, p2.x);
    split2h(v.y, p1.y, p2.y);
    split2h(v.z, p1.z, p2.z);
    split2h(v.w, p1.w, p2.w);
    *(ushort4*)(w1 + (size_t)i * 4) = p1;
    *(ushort4*)(w2 + (size_t)i * 4) = p2;
}

// ---------------------------------------------------------------------------
// h0 = x @ W_in.T + b_in     [4096,256] = [4096,512] @ [512,256]
// (fp32 VALU GEMM, runs once). Split planes are NOT needed here: the LSTM
// cell runs before the logits in every step (incl. step 0) — reference
// semantics; the round-2/3 failure was sampling step 0 from h0 directly.
// ---------------------------------------------------------------------------
__global__ __launch_bounds__(256) void k_h0(const float* __restrict__ x,
                                            const float* __restrict__ W_in,
                                            const float* __restrict__ b_in,
                                            float* __restrict__ h) {
    __shared__ float xs[16 * 512];
    __shared__ float wt[16 * 260];
    const int tid = threadIdx.x;
    const int r0 = blockIdx.x * 16;

#pragma unroll
    for (int p = 0; p < 8; p++) {               // stage x tile [16][512]
        int ff = tid + 256 * p, row = ff >> 7, c4 = ff & 127;
        *(float4*)&xs[row * 512 + c4 * 4] =
            *(const float4*)(x + (size_t)(r0 + row) * 512 + c4 * 4);
    }
    const int g = tid >> 6, l = tid & 63;
    float acc[4][4] = {{0.f}};

    for (int kc = 0; kc < 32; kc++) {
        __syncthreads();
#pragma unroll
        for (int p = 0; p < 4; p++) {           // stage W_in[n][kc*16..] transposed
            int ff = tid + 256 * p, rl = ff >> 2, k4 = ff & 3;
            float4 w = *(const float4*)(W_in + (size_t)rl * 512 + kc * 16 + k4 * 4);
            wt[(k4 * 4 + 0) * 260 + rl] = w.x;
            wt[(k4 * 4 + 1) * 260 + rl] = w.y;
            wt[(k4 * 4 + 2) * 260 + rl] = w.z;
            wt[(k4 * 4 + 3) * 260 + rl] = w.w;
        }
        __syncthreads();
#pragma unroll
        for (int kk = 0; kk < 16; kk += 4) {
            float4 w0 = *(const float4*)&wt[(kk + 0) * 260 + 4 * l];
            float4 w1 = *(const float4*)&wt[(kk + 1) * 260 + 4 * l];
            float4 w2 = *(const float4*)&wt[(kk + 2) * 260 + 4 * l];
            float4 w3 = *(const float4*)&wt[(kk + 3) * 260 + 4 * l];
#pragma unroll
            for (int b = 0; b < 4; b++) {
                float4 xb = *(const float4*)&xs[(4 * g + b) * 512 + kc * 16 + kk];
                acc[b][0] = fmaf(xb.w, w3.x, fmaf(xb.z, w2.x, fmaf(xb.y, w1.x, fmaf(xb.x, w0.x, acc[b][0]))));
                acc[b][1] = fmaf(xb.w, w3.y, fmaf(xb.z, w2.y, fmaf(xb.y, w1.y, fmaf(xb.x, w0.y, acc[b][1]))));
                acc[b][2] = fmaf(xb.w, w3.z, fmaf(xb.z, w2.z, fmaf(xb.y, w1.z, fmaf(xb.x, w0.z, acc[b][2]))));
                acc[b][3] = fmaf(xb.w, w3.w, fmaf(xb.z, w2.w, fmaf(xb.y, w1.w, fmaf(xb.x, w0.w, acc[b][3]))));
            }
        }
    }
    float4 bi = *(const float4*)(b_in + 4 * l);
#pragma unroll
    for (int b = 0; b < 4; b++) {
        float4 o = make_float4(acc[b][0] + bi.x, acc[b][1] + bi.y,
                               acc[b][2] + bi.z, acc[b][3] + bi.w);
        *(float4*)(h + (size_t)(r0 + 4 * g + b) * 256 + 4 * l) = o;
    }
}

// ---------------------------------------------------------------------------
// gates = inp @ W_ih.T + b_ih + h @ W_hh.T + b_hh, fused LSTM cell update,
// + f16x2 split-plane epilogue for the new h. Runs EVERY step (incl. t=0).
// ---------------------------------------------------------------------------
__global__ __launch_bounds__(256) void k_gates_lstm(
    const float* __restrict__ inp, const float* __restrict__ hcur,
    const float* __restrict__ W_ih, const float* __restrict__ W_hh,
    const float* __restrict__ b_ih, const float* __restrict__ b_hh,
    float* __restrict__ c, float* __restrict__ hnxt,
    unsigned short* __restrict__ hsp1, unsigned short* __restrict__ hsp2) {
    __shared__ float xs[16 * 384];
    __shared__ float wt[32 * 260];      // reused as gl[16*256] for the exchange
    const int tid = threadIdx.x;
    const int r0 = blockIdx.x * 16;
    const int u0 = blockIdx.y * 64;

#pragma unroll
    for (int p = 0; p < 2; p++) {               // stage inp [16][128] -> cols [0,128)
        int ff = tid + 256 * p, row = ff >> 5, c4 = ff & 31;
        *(float4*)&xs[row * 384 + c4 * 4] =
            *(const float4*)(inp + (size_t)(r0 + row) * 128 + c4 * 4);
    }
#pragma unroll
    for (int p = 0; p < 4; p++) {               // stage h [16][256] -> cols [128,384)
        int ff = tid + 256 * p, row = ff >> 6, c4 = ff & 63;
        *(float4*)&xs[row * 384 + 128 + c4 * 4] =
            *(const float4*)(hcur + (size_t)(r0 + row) * 256 + c4 * 4);
    }
    const int g = tid >> 6, l = tid & 63;
    float acc[4][4] = {{0.f}};

    for (int kc = 0; kc < 12; kc++) {
        __syncthreads();
        {
            const float* src; int rowlen, koff;
            if (kc < 4) { src = W_ih; rowlen = 128; koff = kc * 32; }
            else        { src = W_hh; rowlen = 256; koff = (kc - 4) * 32; }
#pragma unroll
            for (int p = 0; p < 8; p++) {
                int rl = (tid >> 3) + 32 * p;   // row_local 0..255
                int k4 = tid & 7;
                int grow = ((rl >> 6) << 8) + u0 + (rl & 63);
                float4 w = *(const float4*)(src + (size_t)grow * rowlen + koff + k4 * 4);
                wt[(k4 * 4 + 0) * 260 + rl] = w.x;
                wt[(k4 * 4 + 1) * 260 + rl] = w.y;
                wt[(k4 * 4 + 2) * 260 + rl] = w.z;
                wt[(k4 * 4 + 3) * 260 + rl] = w.w;
            }
        }
        __syncthreads();
#pragma unroll
        for (int kk = 0; kk < 32; kk += 4) {
            float4 w0 = *(const float4*)&wt[(kk + 0) * 260 + 4 * l];
            float4 w1 = *(const float4*)&wt[(kk + 1) * 260 + 4 * l];
            float4 w2 = *(const float4*)&wt[(kk + 2) * 260 + 4 * l];
            float4 w3 = *(const float4*)&wt[(kk + 3) * 260 + 4 * l];
#pragma unroll
            for (int b = 0; b < 4; b++) {
                float4 xb = *(const float4*)&xs[(4 * g + b) * 384 + kc * 32 + kk];
                acc[b][0] = fmaf(xb.w, w3.x, fmaf(xb.z, w2.x, fmaf(xb.y, w1.x, fmaf(xb.x, w0.x, acc[b][0]))));
                acc[b][1] = fmaf(xb.w, w3.y, fmaf(xb.z, w2.y, fmaf(xb.y, w1.y, fmaf(xb.x, w0.y, acc[b][1]))));
                acc[b][2] = fmaf(xb.w, w3.z, fmaf(xb.z, w2.z, fmaf(xb.y, w1.z, fmaf(xb.x, w0.z, acc[b][2]))));
                acc[b][3] = fmaf(xb.w, w3.w, fmaf(xb.z, w2.w, fmaf(xb.y, w1.w, fmaf(xb.x, w0.w, acc[b][3]))));
            }
        }
    }
    {
        int rl0 = 4 * l;
        int grow0 = ((rl0 >> 6) << 8) + u0 + (rl0 & 63);
        float4 bi = *(const float4*)(b_ih + grow0);
        float4 bh = *(const float4*)(b_hh + grow0);
#pragma unroll
        for (int b = 0; b < 4; b++) {
            acc[b][0] += bi.x + bh.x; acc[b][1] += bi.y + bh.y;
            acc[b][2] += bi.z + bh.z; acc[b][3] += bi.w + bh.w;
        }
    }
    __syncthreads();
    float* gl = wt;                              // [16][256]: gate*64+ul per row
#pragma unroll
    for (int b = 0; b < 4; b++)
        *(float4*)&gl[(4 * g + b) * 256 + 4 * l] =
            make_float4(acc[b][0], acc[b][1], acc[b][2], acc[b][3]);
    __syncthreads();
    {   // LSTM pointwise: thread -> (bl = tid>>4, 4 u's)
        int bl = tid >> 4, uq = tid & 15;
        size_t cidx = (size_t)(r0 + bl) * 256 + u0 + uq * 4;
        float4 cold4 = *(float4*)(c + cidx);
        float4 cv, hv;
#pragma unroll
        for (int j = 0; j < 4; j++) {
            int ul = uq * 4 + j;
            float gi = gl[bl * 256 + ul];
            float gf = gl[bl * 256 + 64 + ul];
            float gg = gl[bl * 256 + 128 + ul];
            float go = gl[bl * 256 + 192 + ul];
            float si = fmaf(0.5f, tanhf(0.5f * gi), 0.5f);
            float sf = fmaf(0.5f, tanhf(0.5f * gf), 0.5f);
            float so = fmaf(0.5f, tanhf(0.5f * go), 0.5f);
            float tg = tanhf(gg);
            float cold = (&cold4.x)[j];
            float cn = sf * cold + si * tg;
            (&cv.x)[j] = cn;
            (&hv.x)[j] = so * tanhf(cn);
        }
        *(float4*)(c + cidx) = cv;
        *(float4*)(hnxt + cidx) = hv;
        ushort4 p1, p2;
        split2h(hv.x, p1.x, p2.x);
        split2h(hv.y, p1.y, p2.y);
        split2h(hv.z, p1.z, p2.z);
        split2h(hv.w, p1.w, p2.w);
        *(ushort4*)(hsp1 + cidx) = p1;
        *(ushort4*)(hsp2 + cidx) = p2;
    }
}

// ---------------------------------------------------------------------------
// Fused logits (f16x2 scaled-split MFMA emulation of fp32) + gumbel + stats.
// Mtile 32 x Vtile 128, 4 waves. Wave w: n-range [w*32, w*32+32).
// mfma_f32_16x16x32_f16:
//   A[m=lane&15][k=quad*8+j], B[n=lane&15][k=quad*8+j], D[row=quad*4+reg][col=lane&15]
// 3 MFMA per product into 2 accumulators:
//   acc_hi += a1*b1 ; acc_lo += a1*b2s + a2s*b1 ; logit = acc_hi + acc_lo/2048
// (a2*b2 term ~2^-22 dropped). RMS logit error ~3e-7.
// ---------------------------------------------------------------------------
__global__ __launch_bounds__(256, 3) void k_logits_sample(
    const unsigned short* __restrict__ hsp1, const unsigned short* __restrict__ hsp2,
    const unsigned short* __restrict__ wb1, const unsigned short* __restrict__ wb2,
    const float* __restrict__ b_out, unsigned key0, unsigned key1,
    float* __restrict__ part) {
    // A frags: f = ((kc*2+s)*2+mt), 512 ushorts (64 lanes x 16B) each -> 32KB
    __shared__ unsigned short As[16384];
    const int tid = threadIdx.x;
    const int w = tid >> 6, lane = tid & 63;
    const int quad = lane >> 4, n4 = lane & 15;
    const int r0 = blockIdx.x * 32;
    const int chunk = blockIdx.y;

    // ---- stage A (once): 2048 ushort8 chunks, frag-ordered ----
#pragma unroll
    for (int p = 0; p < 8; p++) {
        int idx8 = tid + 256 * p;               // ushort8 index
        int f = idx8 >> 6, lo = idx8 & 63;
        int kc = f >> 2, s = (f >> 1) & 1, mt = f & 1;
        const unsigned short* hs = s ? hsp2 : hsp1;
        us8 v = *(const us8*)(hs + (size_t)(r0 + mt * 16 + (lo & 15)) * 256
                                 + kc * 32 + (lo >> 4) * 8);
        *(us8*)&As[f * 512 + lo * 8] = v;
    }
    __syncthreads();

    float S[8], Ts[8], U[8], La[8]; int Ai[8];
#pragma unroll
    for (int b = 0; b < 8; b++) { S[b] = 0.f; Ts[b] = 0.f; U[b] = -3.4e38f; La[b] = 0.f; Ai[b] = 0; }

    for (int tile = chunk; tile < NTILES; tile += NCH) {
        const int v0 = tile * 128;
        const int nbase = v0 + w * 32 + n4;
        f32x4 ah[2][2], al[2][2];                // [mt][nt]
#pragma unroll
        for (int mt = 0; mt < 2; mt++)
#pragma unroll
            for (int nt = 0; nt < 2; nt++) {
                ah[mt][nt] = (f32x4){0.f, 0.f, 0.f, 0.f};
                al[mt][nt] = (f32x4){0.f, 0.f, 0.f, 0.f};
            }

#pragma unroll
        for (int kc = 0; kc < 8; kc++) {
            half8 a[2][2];                       // [s][mt]
#pragma unroll
            for (int s = 0; s < 2; s++)
#pragma unroll
                for (int mt = 0; mt < 2; mt++)
                    a[s][mt] = *(const half8*)&As[(((kc * 2 + s) * 2 + mt)) * 512 + lane * 8];
#pragma unroll
            for (int nt = 0; nt < 2; nt++) {
                size_t boff = (size_t)(nbase + nt * 16) * 256 + kc * 32 + quad * 8;
                half8 b1 = *(const half8*)(wb1 + boff);
                half8 b2 = *(const half8*)(wb2 + boff);
#pragma unroll
                for (int mt = 0; mt < 2; mt++) {
                    ah[mt][nt] = __builtin_amdgcn_mfma_f32_16x16x32_f16(a[0][mt], b1, ah[mt][nt], 0, 0, 0);
                    al[mt][nt] = __builtin_amdgcn_mfma_f32_16x16x32_f16(a[0][mt], b2, al[mt][nt], 0, 0, 0);
                    al[mt][nt] = __builtin_amdgcn_mfma_f32_16x16x32_f16(a[1][mt], b1, al[mt][nt], 0, 0, 0);
                }
            }
        }
        // ---- epilogue: identical op sequence to the verified round-1 path ----
#pragma unroll
        for (int nt = 0; nt < 2; nt++) {
            const int v = nbase + nt * 16;
            float bo = b_out[v];
#pragma unroll
            for (int mt = 0; mt < 2; mt++) {
#pragma unroll
                for (int j = 0; j < 4; j++) {
                    float lg = fmaf(RINV, al[mt][nt][j], ah[mt][nt][j]) + bo;
                    float e = __expf(lg - 20.f);
                    int si = mt * 4 + j;
                    S[si] += e;
                    Ts[si] = fmaf(e, lg, Ts[si]);
                    unsigned row = (unsigned)(r0 + mt * 16 + quad * 4 + j);
                    unsigned o0, o1;
                    tf2x32(key0, key1, 0u, row * (unsigned)V + (unsigned)v, o0, o1);
                    unsigned bits = o0 ^ o1;
                    float f = __uint_as_float((bits >> 9) | 0x3f800000u) - 1.0f;
                    float uu = fmaxf(1.17549435e-38f, f + 1.17549435e-38f);
                    float gmb = -logf(-logf(uu));
                    float u = lg + gmb;
                    if (u > U[si] || (u == U[si] && v < Ai[si])) { U[si] = u; Ai[si] = v; La[si] = lg; }
                }
            }
        }
    }
    // 16-lane reduction (lanes n4 share a row within each quad)
#pragma unroll
    for (int si = 0; si < 8; si++) {
        float s = S[si], ts = Ts[si], u = U[si], la = La[si]; int a = Ai[si];
#pragma unroll
        for (int off = 1; off < 16; off <<= 1) {
            s  += __shfl_xor(s, off);
            ts += __shfl_xor(ts, off);
            float u2 = __shfl_xor(u, off);
            float la2 = __shfl_xor(la, off);
            int a2 = __shfl_xor(a, off);
            if (u2 > u || (u2 == u && a2 < a)) { u = u2; a = a2; la = la2; }
        }
        if (n4 == 0) {
            int mt = si >> 2, reg = si & 3;
            int row = r0 + mt * 16 + quad * 4 + reg;
            float* p = part + (size_t)row * NSLOT * 8 + (chunk * 4 + w) * 8;
            p[0] = s; p[1] = ts; p[2] = u; p[3] = la;
            ((int*)p)[4] = a;
        }
    }
}

// ---------------------------------------------------------------------------
// Combine NSLOT partials per row -> sample, logp, entropy, emb gather.
// block: 8 rows x 32 lanes.
// ---------------------------------------------------------------------------
__global__ __launch_bounds__(256) void k_sample_out(
    const float* __restrict__ part, const float* __restrict__ emb,
    float* __restrict__ inp, float* __restrict__ out, int step) {
    const int tid = threadIdx.x;
    const int row = blockIdx.x * 8 + (tid >> 5);
    const int lane = tid & 31;
    const float* p = part + (size_t)row * NSLOT * 8;
    float s = 0.f, ts = 0.f, u = -3.4e38f, la = 0.f; int a = 0;
    for (int cg = 0; cg < NSLOT; cg++) {
        const float* q = p + cg * 8;
        s += q[0]; ts += q[1];
        float uc = q[2]; int ac = ((const int*)q)[4];
        if (uc > u || (uc == u && ac < a)) { u = uc; a = ac; la = q[3]; }
    }
    float lse = logf(s) + 20.f;
    if (lane == 0) {
        out[(size_t)row * OC + step] = (float)a;
        out[(size_t)B * OC + (size_t)row * OC + step] = la - lse;
        out[(size_t)2 * B * OC + (size_t)row * OC + step] = lse - ts / s;
    }
    float4 e4 = *(const float4*)(emb + (size_t)a * 128 + lane * 4);
    *(float4*)&inp[(size_t)row * 128 + lane * 4] = e4;
}

// ---------------------------------------------------------------------------
// Host — LSTM cell runs EVERY step (incl. t=0), then logits from the NEW h.
// ---------------------------------------------------------------------------
extern "C" void kernel_launch(void* const* d_in, const int* in_sizes, int n_in,
                              void* d_out, int out_size, void* d_ws, size_t ws_size,
                              hipStream_t stream) {
    (void)in_sizes; (void)n_in; (void)out_size; (void)ws_size;
    const float* x     = (const float*)d_in[0];
    const float* W_in  = (const float*)d_in[1];
    const float* b_in  = (const float*)d_in[2];
    const float* W_out = (const float*)d_in[3];
    const float* b_out = (const float*)d_in[4];
    const float* emb   = (const float*)d_in[5];
    const float* sos   = (const float*)d_in[6];
    const float* W_ih  = (const float*)d_in[7];
    const float* W_hh  = (const float*)d_in[8];
    const float* b_ih  = (const float*)d_in[9];
    const float* b_hh  = (const float*)d_in[10];
    float* out = (float*)d_out;
    float* ws  = (float*)d_ws;

    float* hA   = ws;                                   // B*H f32
    float* hB   = ws + 1048576;                         // B*H f32
    float* cc   = ws + 2097152;                         // B*H f32
    float* inp  = ws + 3145728;                         // B*E f32
    float* part = ws + 3670016;                         // B * NSLOT * 8 f32
    unsigned short* hsp1 = (unsigned short*)(ws + 4456448);   // B*H ushort
    unsigned short* hsp2 = (unsigned short*)(ws + 4980736);   // B*H ushort
    unsigned short* wb1  = (unsigned short*)(ws + 5505024);   // V*H ushort
    unsigned short* wb2  = (unsigned short*)(ws + 9601024);   // V*H ushort

    // step keys: foldlike split of key(42) = (0,42): key_t = block at (0, t)
    unsigned K0[TT], K1[TT];
    for (int t = 0; t < TT; t++) {
        uint32_t o0, o1;
        tf2x32(0u, 42u, 0u, (uint32_t)t, o0, o1);
        K0[t] = o0; K1[t] = o1;
    }

    k_init<<<4096, 256, 0, stream>>>(cc, inp, sos, out);
    k_wsplit<<<V * H / 4 / 256, 256, 0, stream>>>(W_out, wb1, wb2);
    k_h0<<<B / 16, 256, 0, stream>>>(x, W_in, b_in, hA);

    float* hc = hA;
    float* hn = hB;
    for (int t = 0; t < TT; t++) {
        k_gates_lstm<<<dim3(B / 16, 4), 256, 0, stream>>>(inp, hc, W_ih, W_hh,
                                                          b_ih, b_hh, cc, hn, hsp1, hsp2);
        k_logits_sample<<<dim3(B / 32, NCH), 256, 0, stream>>>(hsp1, hsp2, wb1, wb2,
                                                               b_out, K0[t], K1[t], part);
        k_sample_out<<<B / 8, 256, 0, stream>>>(part, emb, inp, out, t);
        float* tmp = hc; hc = hn; hn = tmp;
    }
}